// Round 18
// baseline (109.078 us; speedup 1.0000x reference)
//
#include <hip/hip_runtime.h>
#include <hip/hip_bf16.h>
#include <stdint.h>

// Problem constants: B=2, T=2048, C=1024, H=16, D=64
#define TT 2048
#define CC 1024
#define NH 16
#define HD 64
#define BT 4096          // B*T rows

typedef float f32x4 __attribute__((ext_vector_type(4)));
typedef __bf16 bf16x8 __attribute__((ext_vector_type(8)));
typedef __bf16 bf16x4 __attribute__((ext_vector_type(4)));
typedef short sh4 __attribute__((ext_vector_type(4)));

#define MFMA(a, b, c) __builtin_amdgcn_mfma_f32_16x16x32_bf16((a), (b), (c), 0, 0, 0)
#define MFMA16(a, b, c) __builtin_amdgcn_mfma_f32_16x16x16bf16_1k((a), (b), (c), 0, 0, 0)

__device__ __forceinline__ void gload16(const void* g, void* l) {
    __builtin_amdgcn_global_load_lds(
        (const __attribute__((address_space(1))) void*)g,
        (__attribute__((address_space(3))) void*)l,
        16, 0, 0);
}

// ------- fused prep: x fp32->bf16 convert + both weight transposes -------
__global__ __launch_bounds__(256) void prep(
    const float* __restrict__ x, __bf16* __restrict__ xb,
    const float* __restrict__ wa, __bf16* __restrict__ oa,
    const float* __restrict__ wp, __bf16* __restrict__ op) {
    __shared__ float tile[32][33];
    int b0 = blockIdx.x;
    if (b0 < 1024) {
        // conv: x [BT*CC] fp32 -> bf16
        int i = b0 * 256 + threadIdx.x;
        const int stride = 1024 * 256;
        const int n4 = BT * CC / 4;
        for (; i < n4; i += stride) {
            float4 v = reinterpret_cast<const float4*>(x)[i];
            bf16x4 o;
            o.x = (__bf16)v.x; o.y = (__bf16)v.y;
            o.z = (__bf16)v.z; o.w = (__bf16)v.w;
            reinterpret_cast<bf16x4*>(xb)[i] = o;
        }
    } else {
        // transpose: w_attn [1024][3072] / w_proj [1024][1024] -> bf16 [C][1024]
        int idx = b0 - 1024;
        int bx = idx & 127, r0 = (idx >> 7) * 32;
        const float* in;
        __bf16* out;
        int C;
        if (bx < 96) { in = wa; out = oa; C = 3072; }
        else         { in = wp; out = op; C = 1024; bx -= 96; }
        int c0 = bx * 32;
        int tx = threadIdx.x & 31, ty = (threadIdx.x >> 5) & 7;
#pragma unroll
        for (int j = 0; j < 32; j += 8)
            tile[ty + j][tx] = in[(size_t)(r0 + ty + j) * C + c0 + tx];
        __syncthreads();
#pragma unroll
        for (int j = 0; j < 32; j += 8)
            out[(size_t)(c0 + ty + j) * 1024 + r0 + tx] = (__bf16)tile[tx][ty + j];
    }
}

// ---------------- bf16 MFMA GEMM, 128x128 tile, BK=64 (m97 structure) ----
// C = A[M,K] * Bt[N,K]^T + bias. MODE 0: scatter q/k -> [B,H,T,D] bf16
// (q scaled by 0.125*log2e for exp2-softmax); v -> [B,H,D,T] bf16 with the
// attention V-swizzle PRE-BAKED per 128B (64-kv) group [r10/r11: conflicts=0].
// MODE 1: fp32 out. XPX = B-panel columns per XCD (xcd = id&7, m09).
template <int MODE, int XPX>
__global__ __launch_bounds__(256) void gemm128(
    const __bf16* __restrict__ A, const __bf16* __restrict__ Bt,
    const float* __restrict__ bias,
    __bf16* __restrict__ oq, __bf16* __restrict__ ok, __bf16* __restrict__ ov,
    float* __restrict__ of, int M, int N, int K) {
    __shared__ __align__(16) __bf16 As[128 * 64];
    __shared__ __align__(16) __bf16 Bs[128 * 64];
    const int tid = threadIdx.x;
    const int w = tid >> 6, lane = tid & 63;
    const int l15 = lane & 15, lg = lane >> 4;
    const int id = blockIdx.x;
    const int jx = id & 7, s = id >> 3;
    const int xcol = jx * XPX + (s % XPX);
    const int yrow = s / XPX;
    const int m0 = yrow * 128, n0 = xcol * 128;
    const int wr = w >> 1, wc = w & 1;

    const f32x4 zero4 = {0.f, 0.f, 0.f, 0.f};
    f32x4 acc[4][4];
#pragma unroll
    for (int m = 0; m < 4; ++m)
#pragma unroll
        for (int n = 0; n < 4; ++n) acc[m][n] = zero4;

    const char* Ab = (const char*)A;
    const char* Bb = (const char*)Bt;
    const size_t rowbytes = (size_t)K * 2;

    for (int kt = 0; kt < K; kt += 64) {
#pragma unroll
        for (int j = 0; j < 4; ++j) {
            int base = (w * 4 + j) * 1024;
            int d0 = base + lane * 16;
            int row = d0 >> 7;
            int colb = d0 & 127;
            int scolb = colb ^ ((row & 7) << 4);
            gload16(Ab + (size_t)(m0 + row) * rowbytes + (size_t)kt * 2 + scolb,
                    (char*)As + base);
            gload16(Bb + (size_t)(n0 + row) * rowbytes + (size_t)kt * 2 + scolb,
                    (char*)Bs + base);
        }
        __syncthreads();
#pragma unroll
        for (int kk = 0; kk < 2; ++kk) {
            bf16x8 af[4], bfr[4];
#pragma unroll
            for (int m = 0; m < 4; ++m) {
                int row = wr * 64 + m * 16 + l15;
                int colb = kk * 64 + lg * 16;
                af[m] = *(const bf16x8*)((const char*)As + row * 128 +
                                         (colb ^ ((row & 7) << 4)));
            }
#pragma unroll
            for (int n = 0; n < 4; ++n) {
                int row = wc * 64 + n * 16 + l15;
                int colb = kk * 64 + lg * 16;
                bfr[n] = *(const bf16x8*)((const char*)Bs + row * 128 +
                                          (colb ^ ((row & 7) << 4)));
            }
#pragma unroll
            for (int m = 0; m < 4; ++m)
#pragma unroll
                for (int n = 0; n < 4; ++n)
                    acc[m][n] = MFMA(af[m], bfr[n], acc[m][n]);
        }
        __syncthreads();
    }

    // epilogue. D layout: col = lane&15, row = (lane>>4)*4 + r  [verified m89/m91]
#pragma unroll
    for (int n = 0; n < 4; ++n) {
        int col = n0 + wc * 64 + n * 16 + l15;
        float bs = bias[col];
        if constexpr (MODE == 0) {
            int sec = col >> 10;          // 0=q 1=k 2=v
            int cc = col & 1023;
            int h = cc >> 6, d = cc & 63;
            if (sec == 2) {
                // V transposed + swizzled: [B,H,D,T], byte addr =
                // base + (t&~63)*2 + ((t&63)*2 ^ ((d&15)<<3)); t 4-aligned
#pragma unroll
                for (int m = 0; m < 4; ++m) {
                    int rowb = m0 + wr * 64 + m * 16 + lg * 4;
                    int bb = rowb >> 11, t = rowb & 2047;
                    bf16x4 pk;
#pragma unroll
                    for (int r = 0; r < 4; ++r) pk[r] = (__bf16)(acc[m][n][r] + bs);
                    size_t base = ((size_t)(bb * NH + h) * HD + d) * (TT * 2);
                    size_t byte = base + (size_t)((t & ~63) * 2 +
                                   (((t & 63) * 2) ^ ((d & 15) << 3)));
                    *(bf16x4*)((char*)ov + byte) = pk;
                }
            } else {
                __bf16* dst = (sec == 0) ? oq : ok;
                // fold softmax scale AND log2(e) into q so attn uses exp2
                float mult = (sec == 0) ? 0.125f * 1.44269504088896340736f : 1.0f;
#pragma unroll
                for (int m = 0; m < 4; ++m) {
                    int rowb = m0 + wr * 64 + m * 16 + lg * 4;
#pragma unroll
                    for (int r = 0; r < 4; ++r) {
                        int row = rowb + r;
                        int bb = row >> 11, t = row & 2047;
                        float val = (acc[m][n][r] + bs) * mult;
                        dst[((size_t)(bb * NH + h) * TT + t) * HD + d] = (__bf16)val;
                    }
                }
            }
        } else {
#pragma unroll
            for (int m = 0; m < 4; ++m) {
                int rowb = m0 + wr * 64 + m * 16 + lg * 4;
#pragma unroll
                for (int r = 0; r < 4; ++r) {
                    int row = rowb + r;
                    of[(size_t)row * N + col] = acc[m][n][r] + bs;
                }
            }
        }
    }
}

// ---------------- causal flash attention (dual q-tile, shared KV) --------
// 512 blocks; block j (0..15 per bh) owns q-tiles (qtA=15-j, qtB=16+j) and
// streams KV ONCE: dual compute while g<=qtA (two independent chains per
// wave -> 2x ILP, K/V LDS reads shared), single (tile B) after. Heavy-first
// dispatch: co-resident block pairs sum to exactly 49 steps. Static softmax
// (r13): no max/rescale; masked s=-1e30 -> exp2 -> 0 exactly. P register-
// resident (MFMA16); V b64 reads conflict-free via producer-baked swizzle.
// LDS 32KB. q,k: [B,H,T,64] bf16 (q pre-scaled). vt: swizzled [B,H,64,T].
__global__ __launch_bounds__(256) void attn_kernel(
    const __bf16* __restrict__ q, const __bf16* __restrict__ k,
    const __bf16* __restrict__ vt, __bf16* __restrict__ y) {
    __shared__ __align__(16) __bf16 Kb[2][64 * 64];   // [kv][d] 128B rows, XOR swz
    __shared__ __align__(16) __bf16 Vb[2][64 * 64];   // [d][kv-swz] 128B rows

    const int n = blockIdx.x;                  // 0..511
    const int sl = (n >> 5) & 7;
    const int j = (n < 256) ? (15 - sl) : sl;  // heavy (j=15..8) first
    const int qtA = 15 - j, qtB = 16 + j;      // light + heavy q-tile
    const int bh = ((n & 7) << 2) | ((n >> 3) & 3);  // 4 heads per XCD slot
    const int tid = threadIdx.x, w = tid >> 6, lane = tid & 63;
    const int l15 = lane & 15, lg = lane >> 4;
    const char* kh = (const char*)(k + (size_t)bh * TT * HD);
    const char* vh = (const char*)(vt + (size_t)bh * HD * TT);
    const __bf16* qh = q + (size_t)bh * TT * HD;
    const int qbwA = qtA * 64 + w * 16;
    const int qbwB = qtB * 64 + w * 16;

    const f32x4 zero4 = {0.f, 0.f, 0.f, 0.f};
    float lrunA = 0.f, lrunB = 0.f;    // per-lane partials (16 k each)
    f32x4 oaccA[4], oaccB[4];          // O^T: col=q=l15, row d = f*16+lg*4+r
    bf16x8 qfA[2], qfB[2];
#pragma unroll
    for (int f = 0; f < 4; ++f) { oaccA[f] = zero4; oaccB[f] = zero4; }
#pragma unroll
    for (int kk = 0; kk < 2; ++kk) {
        qfA[kk] = *(const bf16x8*)&qh[(size_t)(qbwA + l15) * HD + kk * 32 + lg * 8];
        qfB[kk] = *(const bf16x8*)&qh[(size_t)(qbwB + l15) * HD + kk * 32 + lg * 8];
    }

    auto stage = [&](int kvb, int buf) {
#pragma unroll
        for (int jj = 0; jj < 2; ++jj) {
            int d0 = ((w * 2 + jj) * 64 + lane) * 16;
            int row = d0 >> 7, colb = d0 & 127;
            // K: source-XOR swizzle; V: linear (swizzle baked in global layout)
            gload16(kh + (size_t)(kvb + row) * 128 + (colb ^ ((row & 7) << 4)),
                    (char*)Kb[buf] + d0);
            gload16(vh + (size_t)row * (TT * 2) + (size_t)kvb * 2 + colb,
                    (char*)Vb[buf] + d0);
        }
    };

    stage(0, 0);
    __syncthreads();

    for (int g = 0; g <= qtB; ++g) {
        const int cur = g & 1;
        if (g < qtB) stage((g + 1) * 64, cur ^ 1);
        const int kb = g * 64;

        if (g <= qtA) {
            // ======== dual phase: both tiles, shared k/v LDS reads ========
            f32x4 sA[4], sB[4];
#pragma unroll
            for (int kf = 0; kf < 4; ++kf) { sA[kf] = zero4; sB[kf] = zero4; }
            __builtin_amdgcn_s_setprio(1);
#pragma unroll
            for (int kf = 0; kf < 4; ++kf) {
                int krow = kf * 16 + l15;
                const char* kr = (const char*)Kb[cur] + krow * 128;
                bf16x8 k0 = *(const bf16x8*)(kr + ((lg * 16) ^ ((krow & 7) << 4)));
                bf16x8 k1 = *(const bf16x8*)(kr + ((64 + lg * 16) ^ ((krow & 7) << 4)));
                sB[kf] = MFMA(k0, qfB[0], sB[kf]);
                sB[kf] = MFMA(k1, qfB[1], sB[kf]);
                sA[kf] = MFMA(k0, qfA[0], sA[kf]);
                sA[kf] = MFMA(k1, qfA[1], sA[kf]);
            }
            __builtin_amdgcn_s_setprio(0);
            // mask: only tile A's diagonal can occur in dual phase (g<=qtA<qtB)
            if (g == qtA) {
                const int qq = qbwA + l15;
#pragma unroll
                for (int kf = 0; kf < 4; ++kf)
#pragma unroll
                    for (int r = 0; r < 4; ++r) {
                        int kk_ = kb + kf * 16 + lg * 4 + r;
                        if (kk_ > qq) sA[kf][r] = -1e30f;
                    }
            }
            // static softmax both tiles
            sh4 pbA[4], pbB[4];
            float ssA = 0.f, ssB = 0.f;
#pragma unroll
            for (int kf = 0; kf < 4; ++kf) {
                bf16x4 pkA, pkB;
#pragma unroll
                for (int r = 0; r < 4; ++r) {
                    float pB = exp2f(sB[kf][r]);
                    float pA = exp2f(sA[kf][r]);
                    pkB[r] = (__bf16)pB;
                    pkA[r] = (__bf16)pA;
                    ssB += pB;
                    ssA += pA;
                }
                pbB[kf] = __builtin_bit_cast(sh4, pkB);
                pbA[kf] = __builtin_bit_cast(sh4, pkA);
            }
            lrunA += ssA;
            lrunB += ssB;
            // PV both tiles, va loaded once
            __builtin_amdgcn_s_setprio(1);
#pragma unroll
            for (int kf = 0; kf < 4; ++kf) {
                int cb = (kf * 32 + lg * 8) ^ (l15 << 3);
#pragma unroll
                for (int f = 0; f < 4; ++f) {
                    int vrow = f * 16 + l15;
                    bf16x4 va = *(const bf16x4*)((const char*)Vb[cur] + vrow * 128 + cb);
                    sh4 vs = __builtin_bit_cast(sh4, va);
                    oaccB[f] = MFMA16(vs, pbB[kf], oaccB[f]);
                    oaccA[f] = MFMA16(vs, pbA[kf], oaccA[f]);
                }
            }
            __builtin_amdgcn_s_setprio(0);
        } else {
            // ======== single phase: tile B only (r13 body) ========
            f32x4 s[4];
#pragma unroll
            for (int kf = 0; kf < 4; ++kf) s[kf] = zero4;
            __builtin_amdgcn_s_setprio(1);
#pragma unroll
            for (int kf = 0; kf < 4; ++kf) {
                int krow = kf * 16 + l15;
                const char* kr = (const char*)Kb[cur] + krow * 128;
                bf16x8 k0 = *(const bf16x8*)(kr + ((lg * 16) ^ ((krow & 7) << 4)));
                bf16x8 k1 = *(const bf16x8*)(kr + ((64 + lg * 16) ^ ((krow & 7) << 4)));
                s[kf] = MFMA(k0, qfB[0], s[kf]);
                s[kf] = MFMA(k1, qfB[1], s[kf]);
            }
            __builtin_amdgcn_s_setprio(0);
            if (g == qtB) {
                const int qq = qbwB + l15;
#pragma unroll
                for (int kf = 0; kf < 4; ++kf)
#pragma unroll
                    for (int r = 0; r < 4; ++r) {
                        int kk_ = kb + kf * 16 + lg * 4 + r;
                        if (kk_ > qq) s[kf][r] = -1e30f;
                    }
            }
            float ss = 0.f;
            sh4 pb[4];
#pragma unroll
            for (int kf = 0; kf < 4; ++kf) {
                bf16x4 pk;
#pragma unroll
                for (int r = 0; r < 4; ++r) {
                    float p = exp2f(s[kf][r]);
                    pk[r] = (__bf16)p;
                    ss += p;
                }
                pb[kf] = __builtin_bit_cast(sh4, pk);
            }
            lrunB += ss;
            __builtin_amdgcn_s_setprio(1);
#pragma unroll
            for (int kf = 0; kf < 4; ++kf) {
                int cb = (kf * 32 + lg * 8) ^ (l15 << 3);
#pragma unroll
                for (int f = 0; f < 4; ++f) {
                    int vrow = f * 16 + l15;
                    bf16x4 va = *(const bf16x4*)((const char*)Vb[cur] + vrow * 128 + cb);
                    oaccB[f] = MFMA16(__builtin_bit_cast(sh4, va), pb[kf], oaccB[f]);
                }
            }
            __builtin_amdgcn_s_setprio(0);
        }
        __syncthreads();
    }

    // epilogue: finish lrun reductions, write both O^T tiles
    const int b = bh >> 4, h = bh & 15;
    lrunA += __shfl_xor(lrunA, 16);
    lrunA += __shfl_xor(lrunA, 32);
    float invA = 1.0f / lrunA;
#pragma unroll
    for (int f = 0; f < 4; ++f) {
        bf16x4 pk;
#pragma unroll
        for (int r = 0; r < 4; ++r) pk[r] = (__bf16)(oaccA[f][r] * invA);
        *(bf16x4*)&y[(size_t)(b * TT + qbwA + l15) * CC + h * 64 + f * 16 +
                     lg * 4] = pk;
    }
    lrunB += __shfl_xor(lrunB, 16);
    lrunB += __shfl_xor(lrunB, 32);
    float invB = 1.0f / lrunB;
#pragma unroll
    for (int f = 0; f < 4; ++f) {
        bf16x4 pk;
#pragma unroll
        for (int r = 0; r < 4; ++r) pk[r] = (__bf16)(oaccB[f][r] * invB);
        *(bf16x4*)&y[(size_t)(b * TT + qbwB + l15) * CC + h * 64 + f * 16 +
                     lg * 4] = pk;
    }
}

extern "C" void kernel_launch(void* const* d_in, const int* in_sizes, int n_in,
                              void* d_out, int out_size, void* d_ws, size_t ws_size,
                              hipStream_t stream) {
    const float* x      = (const float*)d_in[0];
    const float* w_attn = (const float*)d_in[1];
    const float* b_attn = (const float*)d_in[2];
    const float* w_proj = (const float*)d_in[3];
    const float* b_proj = (const float*)d_in[4];
    float* out = (float*)d_out;

    char* ws = (char*)d_ws;
    size_t off = 0;
    auto alloc = [&](size_t bytes) {
        char* p = ws + off;
        off += (bytes + 255) & ~(size_t)255;
        return p;
    };
    __bf16* xb   = (__bf16*)alloc((size_t)BT * CC * 2);
    __bf16* watb = (__bf16*)alloc((size_t)3 * CC * CC * 2);
    __bf16* wptb = (__bf16*)alloc((size_t)CC * CC * 2);
    __bf16* qb   = (__bf16*)alloc((size_t)BT * CC * 2);
    __bf16* kbuf = (__bf16*)alloc((size_t)BT * CC * 2);
    __bf16* vtb  = (__bf16*)alloc((size_t)BT * CC * 2);  // [B,H,D,T] swizzled
    __bf16* yb   = (__bf16*)alloc((size_t)BT * CC * 2);

    prep<<<5120, 256, 0, stream>>>(x, xb, w_attn, watb, w_proj, wptb);

    // gemm0: N=3072 -> 24 B-panel columns, 3 per XCD; 1-D grid 768
    gemm128<0, 3><<<768, 256, 0, stream>>>(
        xb, watb, b_attn, qb, kbuf, vtb, nullptr, BT, 3 * CC, CC);

    attn_kernel<<<512, 256, 0, stream>>>(qb, kbuf, vtb, yb);

    // gemm1: N=1024 -> 8 B-panel columns, 1 per XCD; 1-D grid 256
    gemm128<1, 1><<<256, 256, 0, stream>>>(
        yb, wptb, b_proj, nullptr, nullptr, nullptr, out, BT, CC, CC);
}

// Round 19
// 108.067 us; speedup vs baseline: 1.0094x; 1.0094x over previous
//
#include <hip/hip_runtime.h>
#include <hip/hip_bf16.h>
#include <stdint.h>

// Problem constants: B=2, T=2048, C=1024, H=16, D=64
#define TT 2048
#define CC 1024
#define NH 16
#define HD 64
#define BT 4096          // B*T rows

typedef float f32x4 __attribute__((ext_vector_type(4)));
typedef __bf16 bf16x8 __attribute__((ext_vector_type(8)));
typedef __bf16 bf16x4 __attribute__((ext_vector_type(4)));
typedef short sh4 __attribute__((ext_vector_type(4)));

#define MFMA(a, b, c) __builtin_amdgcn_mfma_f32_16x16x32_bf16((a), (b), (c), 0, 0, 0)
#define MFMA16(a, b, c) __builtin_amdgcn_mfma_f32_16x16x16bf16_1k((a), (b), (c), 0, 0, 0)

__device__ __forceinline__ void gload16(const void* g, void* l) {
    __builtin_amdgcn_global_load_lds(
        (const __attribute__((address_space(1))) void*)g,
        (__attribute__((address_space(3))) void*)l,
        16, 0, 0);
}

// ------- fused prep: x fp32->bf16 convert + both weight transposes -------
__global__ __launch_bounds__(256) void prep(
    const float* __restrict__ x, __bf16* __restrict__ xb,
    const float* __restrict__ wa, __bf16* __restrict__ oa,
    const float* __restrict__ wp, __bf16* __restrict__ op) {
    __shared__ float tile[32][33];
    int b0 = blockIdx.x;
    if (b0 < 1024) {
        // conv: x [BT*CC] fp32 -> bf16
        int i = b0 * 256 + threadIdx.x;
        const int stride = 1024 * 256;
        const int n4 = BT * CC / 4;
        for (; i < n4; i += stride) {
            float4 v = reinterpret_cast<const float4*>(x)[i];
            bf16x4 o;
            o.x = (__bf16)v.x; o.y = (__bf16)v.y;
            o.z = (__bf16)v.z; o.w = (__bf16)v.w;
            reinterpret_cast<bf16x4*>(xb)[i] = o;
        }
    } else {
        // transpose: w_attn [1024][3072] / w_proj [1024][1024] -> bf16 [C][1024]
        int idx = b0 - 1024;
        int bx = idx & 127, r0 = (idx >> 7) * 32;
        const float* in;
        __bf16* out;
        int C;
        if (bx < 96) { in = wa; out = oa; C = 3072; }
        else         { in = wp; out = op; C = 1024; bx -= 96; }
        int c0 = bx * 32;
        int tx = threadIdx.x & 31, ty = (threadIdx.x >> 5) & 7;
#pragma unroll
        for (int j = 0; j < 32; j += 8)
            tile[ty + j][tx] = in[(size_t)(r0 + ty + j) * C + c0 + tx];
        __syncthreads();
#pragma unroll
        for (int j = 0; j < 32; j += 8)
            out[(size_t)(c0 + ty + j) * 1024 + r0 + tx] = (__bf16)tile[tx][ty + j];
    }
}

// ---------------- bf16 MFMA GEMM, 128x128 tile, BK=64 (m97 structure) ----
// C = A[M,K] * Bt[N,K]^T + bias. MODE 0: scatter q/k -> [B,H,T,D] bf16
// (q scaled by 0.125*log2e for exp2-softmax); v -> [B,H,D,T] bf16 with the
// attention V-swizzle PRE-BAKED per 128B (64-kv) group [r10/r11: conflicts=0].
// MODE 1: fp32 out. XPX = B-panel columns per XCD (xcd = id&7, m09).
template <int MODE, int XPX>
__global__ __launch_bounds__(256) void gemm128(
    const __bf16* __restrict__ A, const __bf16* __restrict__ Bt,
    const float* __restrict__ bias,
    __bf16* __restrict__ oq, __bf16* __restrict__ ok, __bf16* __restrict__ ov,
    float* __restrict__ of, int M, int N, int K) {
    __shared__ __align__(16) __bf16 As[128 * 64];
    __shared__ __align__(16) __bf16 Bs[128 * 64];
    const int tid = threadIdx.x;
    const int w = tid >> 6, lane = tid & 63;
    const int l15 = lane & 15, lg = lane >> 4;
    const int id = blockIdx.x;
    const int jx = id & 7, s = id >> 3;
    const int xcol = jx * XPX + (s % XPX);
    const int yrow = s / XPX;
    const int m0 = yrow * 128, n0 = xcol * 128;
    const int wr = w >> 1, wc = w & 1;

    const f32x4 zero4 = {0.f, 0.f, 0.f, 0.f};
    f32x4 acc[4][4];
#pragma unroll
    for (int m = 0; m < 4; ++m)
#pragma unroll
        for (int n = 0; n < 4; ++n) acc[m][n] = zero4;

    const char* Ab = (const char*)A;
    const char* Bb = (const char*)Bt;
    const size_t rowbytes = (size_t)K * 2;

    for (int kt = 0; kt < K; kt += 64) {
#pragma unroll
        for (int j = 0; j < 4; ++j) {
            int base = (w * 4 + j) * 1024;
            int d0 = base + lane * 16;
            int row = d0 >> 7;
            int colb = d0 & 127;
            int scolb = colb ^ ((row & 7) << 4);
            gload16(Ab + (size_t)(m0 + row) * rowbytes + (size_t)kt * 2 + scolb,
                    (char*)As + base);
            gload16(Bb + (size_t)(n0 + row) * rowbytes + (size_t)kt * 2 + scolb,
                    (char*)Bs + base);
        }
        __syncthreads();
#pragma unroll
        for (int kk = 0; kk < 2; ++kk) {
            bf16x8 af[4], bfr[4];
#pragma unroll
            for (int m = 0; m < 4; ++m) {
                int row = wr * 64 + m * 16 + l15;
                int colb = kk * 64 + lg * 16;
                af[m] = *(const bf16x8*)((const char*)As + row * 128 +
                                         (colb ^ ((row & 7) << 4)));
            }
#pragma unroll
            for (int n = 0; n < 4; ++n) {
                int row = wc * 64 + n * 16 + l15;
                int colb = kk * 64 + lg * 16;
                bfr[n] = *(const bf16x8*)((const char*)Bs + row * 128 +
                                          (colb ^ ((row & 7) << 4)));
            }
#pragma unroll
            for (int m = 0; m < 4; ++m)
#pragma unroll
                for (int n = 0; n < 4; ++n)
                    acc[m][n] = MFMA(af[m], bfr[n], acc[m][n]);
        }
        __syncthreads();
    }

    // epilogue. D layout: col = lane&15, row = (lane>>4)*4 + r  [verified m89/m91]
#pragma unroll
    for (int n = 0; n < 4; ++n) {
        int col = n0 + wc * 64 + n * 16 + l15;
        float bs = bias[col];
        if constexpr (MODE == 0) {
            int sec = col >> 10;          // 0=q 1=k 2=v
            int cc = col & 1023;
            int h = cc >> 6, d = cc & 63;
            if (sec == 2) {
                // V transposed + swizzled: [B,H,D,T], byte addr =
                // base + (t&~63)*2 + ((t&63)*2 ^ ((d&15)<<3)); t 4-aligned
#pragma unroll
                for (int m = 0; m < 4; ++m) {
                    int rowb = m0 + wr * 64 + m * 16 + lg * 4;
                    int bb = rowb >> 11, t = rowb & 2047;
                    bf16x4 pk;
#pragma unroll
                    for (int r = 0; r < 4; ++r) pk[r] = (__bf16)(acc[m][n][r] + bs);
                    size_t base = ((size_t)(bb * NH + h) * HD + d) * (TT * 2);
                    size_t byte = base + (size_t)((t & ~63) * 2 +
                                   (((t & 63) * 2) ^ ((d & 15) << 3)));
                    *(bf16x4*)((char*)ov + byte) = pk;
                }
            } else {
                __bf16* dst = (sec == 0) ? oq : ok;
                // fold softmax scale AND log2(e) into q so attn uses exp2
                float mult = (sec == 0) ? 0.125f * 1.44269504088896340736f : 1.0f;
#pragma unroll
                for (int m = 0; m < 4; ++m) {
                    int rowb = m0 + wr * 64 + m * 16 + lg * 4;
#pragma unroll
                    for (int r = 0; r < 4; ++r) {
                        int row = rowb + r;
                        int bb = row >> 11, t = row & 2047;
                        float val = (acc[m][n][r] + bs) * mult;
                        dst[((size_t)(bb * NH + h) * TT + t) * HD + d] = (__bf16)val;
                    }
                }
            }
        } else {
#pragma unroll
            for (int m = 0; m < 4; ++m) {
                int rowb = m0 + wr * 64 + m * 16 + lg * 4;
#pragma unroll
                for (int r = 0; r < 4; ++r) {
                    int row = rowb + r;
                    of[(size_t)row * N + col] = acc[m][n][r] + bs;
                }
            }
        }
    }
}

// ---------------- causal flash attention (r13 + T15 step-pipeline) -------
// One q-tile (64 rows, 4 waves x 16) per block; 1024 blocks; balanced
// mapping {31-a,16+a,15-a,a} (CU slot-groups sum to 62 steps); 4 heads per
// XCD slot. Static softmax (no max/rescale; masked -1e30 -> exp2 -> 0).
// P register-resident (MFMA16); V b64 conflict-free via producer-baked
// swizzle. T15: 3-buffer K/V, tile t's loads issue at top of step t-2 and
// the end-of-step vmcnt(0) drains loads aged a full step (~free); K[g+1]
// is thus valid DURING step g, so S_next=QK^T(K[g+1]) overlaps softmax's
// 16-exp2 TRANS chain + PV of tile g (independent chains). LDS 48KB.
// q,k: [B,H,T,64] bf16 (q pre-scaled by 0.125*log2e). vt: swizzled [B,H,64,T].
__global__ __launch_bounds__(256) void attn_kernel(
    const __bf16* __restrict__ q, const __bf16* __restrict__ k,
    const __bf16* __restrict__ vt, __bf16* __restrict__ y) {
    __shared__ __align__(16) __bf16 Kb[3][64 * 64];   // [kv][d] 128B rows, XOR swz
    __shared__ __align__(16) __bf16 Vb[3][64 * 64];   // [d][kv-swz] 128B rows

    const int n = blockIdx.x;
    const int batch = n >> 8, a = (n >> 5) & 7;
    const int qt = (batch == 0) ? 31 - a : (batch == 1) ? 16 + a
                 : (batch == 2) ? 15 - a : a;
    const int bh = ((n & 7) << 2) | ((n >> 3) & 3);  // 4 heads per XCD slot
    const int tid = threadIdx.x, w = tid >> 6, lane = tid & 63;
    const int l15 = lane & 15, lg = lane >> 4;
    const char* kh = (const char*)(k + (size_t)bh * TT * HD);
    const char* vh = (const char*)(vt + (size_t)bh * HD * TT);
    const __bf16* qh = q + (size_t)bh * TT * HD;
    const int qbw = qt * 64 + w * 16;

    const f32x4 zero4 = {0.f, 0.f, 0.f, 0.f};
    float lrun = 0.f;                  // per-lane partial (16 k each)
    f32x4 oacc[4];                     // O^T: col=q=l15, row d = f*16+lg*4+r
    bf16x8 qf[2];
#pragma unroll
    for (int f = 0; f < 4; ++f) oacc[f] = zero4;
#pragma unroll
    for (int kk = 0; kk < 2; ++kk)
        qf[kk] = *(const bf16x8*)&qh[(size_t)(qbw + l15) * HD + kk * 32 + lg * 8];

    auto stage = [&](int kvb, int buf) {
#pragma unroll
        for (int j = 0; j < 2; ++j) {
            int d0 = ((w * 2 + j) * 64 + lane) * 16;
            int row = d0 >> 7, colb = d0 & 127;
            // K: source-XOR swizzle; V: linear (swizzle baked in global layout)
            gload16(kh + (size_t)(kvb + row) * 128 + (colb ^ ((row & 7) << 4)),
                    (char*)Kb[buf] + d0);
            gload16(vh + (size_t)row * (TT * 2) + (size_t)kvb * 2 + colb,
                    (char*)Vb[buf] + d0);
        }
    };
    // S^T = K Q^T from LDS buffer `buf` (col=q=l15, row k = kf*16+lg*4+r)
    auto qkt = [&](int buf, f32x4 (&sout)[4]) {
#pragma unroll
        for (int kf = 0; kf < 4; ++kf) sout[kf] = zero4;
#pragma unroll
        for (int kf = 0; kf < 4; ++kf) {
            int krow = kf * 16 + l15;
            const char* kr = (const char*)Kb[buf] + krow * 128;
            bf16x8 k0 = *(const bf16x8*)(kr + ((lg * 16) ^ ((krow & 7) << 4)));
            bf16x8 k1 = *(const bf16x8*)(kr + ((64 + lg * 16) ^ ((krow & 7) << 4)));
            sout[kf] = MFMA(k0, qf[0], sout[kf]);
            sout[kf] = MFMA(k1, qf[1], sout[kf]);
        }
    };

    // prologue: stage tiles 0 and 1; drain; precompute S_cur from tile 0
    stage(0, 0);
    if (qt > 0) stage(64, 1);
    asm volatile("s_waitcnt vmcnt(0)" ::: "memory");
    __builtin_amdgcn_sched_barrier(0);
    __builtin_amdgcn_s_barrier();

    f32x4 scur[4];
    qkt(0, scur);

    for (int g = 0; g <= qt; ++g) {
        const int cur = g % 3;
        if (g + 2 <= qt) stage((g + 2) * 64, (g + 2) % 3);

        // ---- S_next = QK^T(K[g+1]) — overlaps softmax+PV below ----
        f32x4 snext[4];
        __builtin_amdgcn_s_setprio(1);
        if (g < qt) qkt((g + 1) % 3, snext);
        __builtin_amdgcn_s_setprio(0);

        // ---- causal mask (diagonal tile only, applied at consume time) ----
        if (g == qt) {
            const int kb = g * 64;
            const int qq = qbw + l15;
#pragma unroll
            for (int kf = 0; kf < 4; ++kf)
#pragma unroll
                for (int r = 0; r < 4; ++r) {
                    int kk_ = kb + kf * 16 + lg * 4 + r;
                    if (kk_ > qq) scur[kf][r] = -1e30f;
                }
        }
        // ---- static softmax: P = exp2(s), no max shift, no rescale ----
        float ss = 0.f;
        sh4 pb[4];                         // P^T bf16, register-resident
#pragma unroll
        for (int kf = 0; kf < 4; ++kf) {
            bf16x4 pk;
#pragma unroll
            for (int r = 0; r < 4; ++r) {
                float p = exp2f(scur[kf][r]);   // masked (-1e30) -> 0 exactly
                pk[r] = (__bf16)p;
                ss += p;
            }
            pb[kf] = __builtin_bit_cast(sh4, pk);
        }
        lrun += ss;                        // cross-lane sum deferred to epilogue
        // ---- O^T += V^T P ---- 16x16x16: A=V^T (k=lg*4+j via baked swizzle)
        __builtin_amdgcn_s_setprio(1);
#pragma unroll
        for (int kf = 0; kf < 4; ++kf) {
            int cb = (kf * 32 + lg * 8) ^ (l15 << 3);
#pragma unroll
            for (int f = 0; f < 4; ++f) {
                int vrow = f * 16 + l15;
                bf16x4 va = *(const bf16x4*)((const char*)Vb[cur] + vrow * 128 + cb);
                oacc[f] = MFMA16(__builtin_bit_cast(sh4, va), pb[kf], oacc[f]);
            }
        }
        __builtin_amdgcn_s_setprio(0);

        if (g < qt) {
            // drain: only loads issued >= one step ago remain (near-free)
            asm volatile("s_waitcnt vmcnt(0)" ::: "memory");
            __builtin_amdgcn_sched_barrier(0);
            __builtin_amdgcn_s_barrier();
#pragma unroll
            for (int kf = 0; kf < 4; ++kf) scur[kf] = snext[kf];
        }
    }

    // epilogue: finish the lrun reduction across the 4 lg groups, write O^T
    lrun += __shfl_xor(lrun, 16);
    lrun += __shfl_xor(lrun, 32);
    const int b = bh >> 4, h = bh & 15;
    float inv = 1.0f / lrun;
#pragma unroll
    for (int f = 0; f < 4; ++f) {
        bf16x4 pk;
#pragma unroll
        for (int r = 0; r < 4; ++r) pk[r] = (__bf16)(oacc[f][r] * inv);
        *(bf16x4*)&y[(size_t)(b * TT + qbw + l15) * CC + h * 64 + f * 16 +
                     lg * 4] = pk;
    }
}

extern "C" void kernel_launch(void* const* d_in, const int* in_sizes, int n_in,
                              void* d_out, int out_size, void* d_ws, size_t ws_size,
                              hipStream_t stream) {
    const float* x      = (const float*)d_in[0];
    const float* w_attn = (const float*)d_in[1];
    const float* b_attn = (const float*)d_in[2];
    const float* w_proj = (const float*)d_in[3];
    const float* b_proj = (const float*)d_in[4];
    float* out = (float*)d_out;

    char* ws = (char*)d_ws;
    size_t off = 0;
    auto alloc = [&](size_t bytes) {
        char* p = ws + off;
        off += (bytes + 255) & ~(size_t)255;
        return p;
    };
    __bf16* xb   = (__bf16*)alloc((size_t)BT * CC * 2);
    __bf16* watb = (__bf16*)alloc((size_t)3 * CC * CC * 2);
    __bf16* wptb = (__bf16*)alloc((size_t)CC * CC * 2);
    __bf16* qb   = (__bf16*)alloc((size_t)BT * CC * 2);
    __bf16* kbuf = (__bf16*)alloc((size_t)BT * CC * 2);
    __bf16* vtb  = (__bf16*)alloc((size_t)BT * CC * 2);  // [B,H,D,T] swizzled
    __bf16* yb   = (__bf16*)alloc((size_t)BT * CC * 2);

    prep<<<5120, 256, 0, stream>>>(x, xb, w_attn, watb, w_proj, wptb);

    // gemm0: N=3072 -> 24 B-panel columns, 3 per XCD; 1-D grid 768
    gemm128<0, 3><<<768, 256, 0, stream>>>(
        xb, watb, b_attn, qb, kbuf, vtb, nullptr, BT, 3 * CC, CC);

    attn_kernel<<<1024, 256, 0, stream>>>(qb, kbuf, vtb, yb);

    // gemm1: N=1024 -> 8 B-panel columns, 1 per XCD; 1-D grid 256
    gemm128<1, 1><<<256, 256, 0, stream>>>(
        yb, wptb, b_proj, nullptr, nullptr, nullptr, out, BT, CC, CC);
}